// Round 3
// baseline (343.506 us; speedup 1.0000x reference)
//
#include <hip/hip_runtime.h>
#include <math.h>

#define G 512
#define N 400
#define D 128
#define K 200
#define DOUT 512
#define DMID 32
#define GK (G*K)      // 102400
#define KD (K*D)      // 25600
#define NCHUNK 200    // GEMM2 k-chunks of 128

#define SH  129       // sHt stride (GEMM2)
#define SW2 36        // padded stride for W2T tile (GEMM2)

#define NT 13         // m-tiles of 32 rows in gemm1_pool (416 slots, 400 valid)
#define TPB 512       // threads per block of gemm1_pool (8 waves)

// dynamic LDS layout for gemm1_pool (bytes):
//   float  s_acc[200][128]   102400
//   ushort sAhi[2][8][64][8]  16384
//   ushort sAlo[2][8][64][8]  16384
//   int    s_ids[400]          1600
//   int    s_cnt[200]           800
//   float  s_inv[200]           800
#define G1_LDS (102400 + 16384 + 16384 + 1600 + 800 + 800)  // 138368

__device__ __forceinline__ float relu(float v) { return fmaxf(v, 0.0f); }

typedef __attribute__((ext_vector_type(8))) short short8b;   // 8 bf16 = 4 VGPR
typedef __attribute__((ext_vector_type(16))) float floatx16; // mfma 32x32 acc

__device__ __forceinline__ ushort f2bf(float f) {  // fp32 -> bf16 (RNE)
  unsigned u = __float_as_uint(f);
  unsigned r = (u + 0x7FFFu + ((u >> 16) & 1u)) >> 16;
  return (ushort)r;
}
__device__ __forceinline__ float bf2f(ushort h) {
  return __uint_as_float(((unsigned)h) << 16);
}

// Native non-returning LDS float add (single DS op, no CAS retry loop).
__device__ __forceinline__ void lds_fadd(float* p, float v) {
  asm volatile("ds_add_f32 %0, %1"
               :
               : "v"((unsigned)(unsigned long long)p), "v"(v)
               : "memory");
}

// ---------------- K1b: W1 -> fragment-major hi/lo bf16 (B-operand prep) ----------------
// layout: wh[nt][ks][l][i] holds W1[k*D + n], k = ks*16 + (l>>5)*8 + i, n = nt*32 + (l&31)
__global__ __launch_bounds__(256) void w1prep(
    const float* __restrict__ W1, ushort* __restrict__ wh, ushort* __restrict__ wl) {
  const int idx = blockIdx.x * 256 + threadIdx.x;  // < 16384
  const int i = idx & 7, l = (idx >> 3) & 63, ks = (idx >> 9) & 7, nt = idx >> 12;
  const int k = ks * 16 + (l >> 5) * 8 + i;
  const int n = nt * 32 + (l & 31);
  const float v = W1[k * D + n];
  const ushort h = f2bf(v);
  wh[idx] = h;
  wl[idx] = f2bf(v - bf2f(h));
}

// ---------------- K1: dense GEMM (x @ W1) then segment-mean pooling ----------------
// One block per g, 8 waves. y = x@W1 computed tile-by-tile via split-bf16 MFMA;
// accumulator fragments scattered into s_acc[cluster][n] via native ds_add_f32
// (linearity: mean(x)@W1 == mean(x@W1)). Epilogue: 1/cnt, +b1, relu, f4 store.
// Wave w: n-tile nt = w&3, ks-halves ksbase = (w>>2)*4 (two waves share an n-tile,
// split over K; partial sums combine in the LDS atomic scatter).
// __launch_bounds__(TPB, 1): LDS (138 KB) caps residency at 1 block/CU, so demand
// the full-register allocation — (TPB, 2) gave a 64-reg unified budget (48 VGPR +
// 16 AGPR observed) and spilled the whole working set to scratch (the 310 us bug).
__global__ __launch_bounds__(TPB, 1) void gemm1_pool(
    const float* __restrict__ x, const int* __restrict__ cluster,
    const ushort* __restrict__ wh, const ushort* __restrict__ wl,
    const float* __restrict__ b1, float* __restrict__ h1) {
  extern __shared__ char smem[];
  float*  s_acc = (float*)smem;                       // [200][128]
  ushort* sAhi  = (ushort*)(smem + 102400);           // [2][8][64][8]
  ushort* sAlo  = sAhi + 2 * 8 * 64 * 8;              // [2][8][64][8]
  int*    s_ids = (int*)(smem + 102400 + 32768);      // [400]
  int*    s_cnt = s_ids + 400;                        // [200]
  float*  s_inv = (float*)(s_cnt + 200);              // [200]

  const int g = blockIdx.x;
  const int tid = threadIdx.x;
  const int lane = tid & 63;
  const int w = tid >> 6;

  const float* xg = x + (size_t)g * N * D;

  // staging unit: (row = tid&31, c = tid>>5), c in 0..15 -> d-range [c*8, c*8+8)
  // frag dest: ks = c>>1 = w, lane' = (c&1)*32 + row = lane  => dest idx = ((buf*8+w)*64+lane)*8
  const int urow = tid & 31, uc = tid >> 5;

#define SLOAD(MT, R0, R1)                                                   \
  {                                                                         \
    int rr = (MT) * 32 + urow; rr = rr < N ? rr : N - 1;                    \
    const float* p = xg + (size_t)rr * D + uc * 8;                          \
    R0 = *(const float4*)p; R1 = *(const float4*)(p + 4);                   \
  }

#define SWRITE(BUF, R0, R1)                                                 \
  {                                                                         \
    float vv[8] = {R0.x, R0.y, R0.z, R0.w, R1.x, R1.y, R1.z, R1.w};         \
    short8b hv, lv;                                                         \
    _Pragma("unroll")                                                       \
    for (int e = 0; e < 8; ++e) {                                           \
      const ushort hh = f2bf(vv[e]);                                        \
      hv[e] = (short)hh;                                                    \
      lv[e] = (short)f2bf(vv[e] - bf2f(hh));                                \
    }                                                                       \
    const int di = (((BUF) * 8 + w) * 64 + lane) * 8;                       \
    *(short8b*)&sAhi[di] = hv;                                              \
    *(short8b*)&sAlo[di] = lv;                                              \
  }

  // ---- prologue: issue tile 0/1 loads early, zero acc/cnt ----
  float4 Ra0, Ra1, Rb0, Rb1;
  SLOAD(0, Ra0, Ra1);
  SLOAD(1, Rb0, Rb1);
  for (int i = tid; i < K * D / 4; i += TPB)
    ((float4*)s_acc)[i] = make_float4(0.f, 0.f, 0.f, 0.f);
  if (tid < K) s_cnt[tid] = 0;
  __syncthreads();  // B1: zeroing done

  if (tid < N) {
    const int id = cluster[g * N + tid];
    s_ids[tid] = id;
    atomicAdd(&s_cnt[id], 1);
  }
  SWRITE(0, Ra0, Ra1);  // tile 0 -> buf 0

  // hoist W1 B-frags for this wave (nt, 4 ks) into registers
  const int nt = w & 3, ksbase = (w >> 2) * 4;
  short8b Bh[4], Bl[4];
#pragma unroll
  for (int kk = 0; kk < 4; ++kk) {
    const int ks = ksbase + kk;
    Bh[kk] = *(const short8b*)&wh[((nt * 8 + ks) * 64 + lane) * 8];
    Bl[kk] = *(const short8b*)&wl[((nt * 8 + ks) * 64 + lane) * 8];
  }
  __syncthreads();  // B2: ids, counts, tile-0 frags ready
  if (tid < K) s_inv[tid] = 1.0f / (float)max(s_cnt[tid], 1);

  const int col = lane & 31;
  const int rbase4 = 4 * (lane >> 5);

  // ---- main loop: 1 barrier per tile; loads issued 1 tile ahead of use ----
  for (int mt = 0; mt < NT; ++mt) {
    const int buf = mt & 1;
    if (mt + 2 < NT) {  // issue loads for tile mt+2 first (parity mt&1)
      if (mt & 1) { SLOAD(mt + 2, Rb0, Rb1); } else { SLOAD(mt + 2, Ra0, Ra1); }
    }
    if (mt + 1 < NT) {  // write next tile's frags (data loaded 1 iter ago)
      if ((mt + 1) & 1) { SWRITE(1, Rb0, Rb1); } else { SWRITE(0, Ra0, Ra1); }
    }

    floatx16 acc;
#pragma unroll
    for (int e = 0; e < 16; ++e) acc[e] = 0.0f;

    const ushort* ah0 = &sAhi[((buf * 8 + ksbase) * 64 + lane) * 8];
    const ushort* al0 = &sAlo[((buf * 8 + ksbase) * 64 + lane) * 8];
#pragma unroll
    for (int kk = 0; kk < 4; ++kk) {
      const short8b ah = *(const short8b*)&ah0[kk * 512];
      const short8b al = *(const short8b*)&al0[kk * 512];
      acc = __builtin_amdgcn_mfma_f32_32x32x16_bf16(ah, Bh[kk], acc, 0, 0, 0);
      acc = __builtin_amdgcn_mfma_f32_32x32x16_bf16(ah, Bl[kk], acc, 0, 0, 0);
      acc = __builtin_amdgcn_mfma_f32_32x32x16_bf16(al, Bh[kk], acc, 0, 0, 0);
    }

    // scatter y-fragments into per-cluster accumulator (bank = col: conflict-free)
    const int rowbase = mt * 32 + rbase4;
#pragma unroll
    for (int e = 0; e < 16; ++e) {
      const int r = rowbase + (e & 3) + 8 * (e >> 2);
      if (r < N) {
        const int id = s_ids[r];
        lds_fadd(&s_acc[id * D + nt * 32 + col], acc[e]);
      }
    }
    __syncthreads();
  }

  // drain our untracked asm ds_adds, then make their completion visible block-wide
  asm volatile("s_waitcnt lgkmcnt(0)" ::: "memory");
  __syncthreads();

  // ---- epilogue: mean + bias + relu, coalesced float4 stores ----
  float* og = h1 + (size_t)g * KD;
  for (int i = tid; i < K * D / 4; i += TPB) {
    const int row = i >> 5;
    const float iv = s_inv[row];
    const float4 a = ((const float4*)s_acc)[i];
    const float4 bb = *(const float4*)&b1[(i & 31) * 4];
    float4 o;
    o.x = relu(fmaf(a.x, iv, bb.x));
    o.y = relu(fmaf(a.y, iv, bb.y));
    o.z = relu(fmaf(a.z, iv, bb.z));
    o.w = relu(fmaf(a.w, iv, bb.w));
    ((float4*)og)[i] = o;
  }
#undef SLOAD
#undef SWRITE
}

// ---------------- K3: GEMM2 partials (32-row g-blocks) ----------------
__global__ __launch_bounds__(256) void gemm2_partial(
    const float* __restrict__ h1, const float* __restrict__ W2,
    float* __restrict__ partials) {
  extern __shared__ float smemf[];
  float* sHt = smemf;            // [32][SH]
  float* sWT = smemf + 32 * SH;  // [128][SW2]
  const int kc = blockIdx.x;     // 0..199
  const int gb = blockIdx.y;     // 0..15
  const int k0 = kc * 128, g0 = gb * 32;
  const int tid = threadIdx.x;

  for (int i = tid; i < 32 * 128; i += 256) {
    const int r = i >> 7, k = i & 127;
    sHt[r * SH + k] = h1[(size_t)(g0 + r) * KD + k0 + k];
  }
  for (int i = tid; i < 32 * 128; i += 256) {
    const int j = i >> 7, k = i & 127;
    sWT[k * SW2 + j] = W2[(size_t)j * KD + k0 + k];
  }
  __syncthreads();

  const int jt = tid & 7;   // j block of 4
  const int gt = tid >> 3;  // one g row each (32)
  float acc[4];
#pragma unroll
  for (int j = 0; j < 4; j++) acc[j] = 0.0f;

  for (int k = 0; k < 128; ++k) {
    const float h = sHt[gt * SH + k];
    const float4 w0 = *(const float4*)&sWT[k * SW2 + jt * 4];
    acc[0] = fmaf(h, w0.x, acc[0]); acc[1] = fmaf(h, w0.y, acc[1]);
    acc[2] = fmaf(h, w0.z, acc[2]); acc[3] = fmaf(h, w0.w, acc[3]);
  }

  float* pp = partials + ((size_t)kc * G + g0 + gt) * DMID + jt * 4;
  *(float4*)&pp[0] = make_float4(acc[0], acc[1], acc[2], acc[3]);
}

// ---------------- K4a: reduce stage 1 (200 -> 8), grid (64, 8) ----------------
__global__ __launch_bounds__(256) void gemm2_reduce1(
    const float* __restrict__ partials, float* __restrict__ partials2) {
  const int idx = blockIdx.x * 256 + threadIdx.x;  // < G*DMID
  const int cg = blockIdx.y;                        // 0..7
  float s = 0.0f;
  for (int c = cg * 25; c < cg * 25 + 25; ++c)
    s += partials[(size_t)c * G * DMID + idx];
  partials2[(size_t)cg * G * DMID + idx] = s;
}

// ---------------- K4b: reduce stage 2 (8 -> h2) ----------------
__global__ __launch_bounds__(256) void gemm2_reduce2(
    const float* __restrict__ partials2, const float* __restrict__ b2,
    float* __restrict__ h2) {
  const int idx = blockIdx.x * 256 + threadIdx.x;  // < G*DMID
  const int j = idx & 31;
  float s = 0.0f;
#pragma unroll
  for (int c = 0; c < 8; ++c) s += partials2[(size_t)c * G * DMID + idx];
  h2[idx] = relu(s + b2[j]);
}

// ---------------- K5: GEMM3 + cosine + per-pair squared error ----------------
__global__ __launch_bounds__(256) void head_kernel(
    const float* __restrict__ h2, const float* __restrict__ W3,
    const float* __restrict__ b3, const float* __restrict__ ts,
    float* __restrict__ pair_sq) {
  __shared__ float sA[DMID], sB[DMID];
  __shared__ float rdot[4], rna[4], rnb[4];
  const int p = blockIdx.x;
  const int tid = threadIdx.x;
  if (tid < DMID) sA[tid] = h2[(size_t)(2 * p) * DMID + tid];
  else if (tid < 2 * DMID) sB[tid - DMID] = h2[(size_t)(2 * p + 1) * DMID + (tid - DMID)];
  __syncthreads();

  float dot = 0.0f, na = 0.0f, nb = 0.0f;
#pragma unroll
  for (int rep = 0; rep < 2; ++rep) {
    const int o = rep * 256 + tid;
    const float* w = W3 + (size_t)o * DMID;
    float accA = b3[o], accB = accA;
#pragma unroll
    for (int m = 0; m < DMID; m += 4) {
      const float4 wv = *(const float4*)&w[m];
      accA = fmaf(sA[m], wv.x, accA); accB = fmaf(sB[m], wv.x, accB);
      accA = fmaf(sA[m + 1], wv.y, accA); accB = fmaf(sB[m + 1], wv.y, accB);
      accA = fmaf(sA[m + 2], wv.z, accA); accB = fmaf(sB[m + 2], wv.z, accB);
      accA = fmaf(sA[m + 3], wv.w, accA); accB = fmaf(sB[m + 3], wv.w, accB);
    }
    const float a = relu(accA), b = relu(accB);
    dot = fmaf(a, b, dot); na = fmaf(a, a, na); nb = fmaf(b, b, nb);
  }
#pragma unroll
  for (int off = 32; off >= 1; off >>= 1) {
    dot += __shfl_down(dot, off);
    na  += __shfl_down(na, off);
    nb  += __shfl_down(nb, off);
  }
  const int wave = tid >> 6, lane = tid & 63;
  if (lane == 0) { rdot[wave] = dot; rna[wave] = na; rnb[wave] = nb; }
  __syncthreads();
  if (tid == 0) {
    const float dt = rdot[0] + rdot[1] + rdot[2] + rdot[3];
    const float nA = rna[0] + rna[1] + rna[2] + rna[3];
    const float nB = rnb[0] + rnb[1] + rnb[2] + rnb[3];
    const float n1 = fmaxf(sqrtf(nA), 1e-6f);
    const float n2 = fmaxf(sqrtf(nB), 1e-6f);
    const float sc = dt / (n1 * n2);
    const float e = sc - ts[p];
    pair_sq[p] = e * e;
  }
}

// ---------------- K6: final mean ----------------
__global__ __launch_bounds__(256) void loss_kernel(
    const float* __restrict__ pair_sq, float* __restrict__ out) {
  __shared__ float red[4];
  const int tid = threadIdx.x;
  float v = pair_sq[tid];
#pragma unroll
  for (int off = 32; off >= 1; off >>= 1) v += __shfl_down(v, off);
  const int wave = tid >> 6, lane = tid & 63;
  if (lane == 0) red[wave] = v;
  __syncthreads();
  if (tid == 0) out[0] = (red[0] + red[1] + red[2] + red[3]) * (1.0f / 256.0f);
}

extern "C" void kernel_launch(void* const* d_in, const int* in_sizes, int n_in,
                              void* d_out, int out_size, void* d_ws, size_t ws_size,
                              hipStream_t stream) {
  const float* x       = (const float*)d_in[0];
  const int*   cluster = (const int*)d_in[1];
  const float* ts      = (const float*)d_in[2];
  const float* W1      = (const float*)d_in[3];
  const float* b1      = (const float*)d_in[4];
  const float* W2      = (const float*)d_in[5];
  const float* b2      = (const float*)d_in[6];
  const float* W3      = (const float*)d_in[7];
  const float* b3      = (const float*)d_in[8];

  float* ws = (float*)d_ws;
  float* h1        = ws;                                   // GK*D
  float* partials  = h1 + (size_t)GK * D;                  // NCHUNK*G*DMID
  float* h2        = partials + (size_t)NCHUNK * G * DMID; // G*DMID
  float* pair_sq   = h2 + (size_t)G * DMID;                // 256
  float* partials2 = pair_sq + 256;                        // 8*G*DMID
  ushort* wfrag_hi = (ushort*)(partials2 + 8 * G * DMID);  // 16384 bf16
  ushort* wfrag_lo = wfrag_hi + 16384;                     // 16384 bf16

  // allow >64 KB dynamic LDS for gemm1_pool (host-side attr, graph-capture safe)
  static bool attr_set = false;
  if (!attr_set) {
    (void)hipFuncSetAttribute((const void*)gemm1_pool,
                              hipFuncAttributeMaxDynamicSharedMemorySize,
                              160 * 1024);
    attr_set = true;
  }

  w1prep<<<16384 / 256, 256, 0, stream>>>(W1, wfrag_hi, wfrag_lo);
  gemm1_pool<<<G, TPB, G1_LDS, stream>>>(x, cluster, wfrag_hi, wfrag_lo, b1, h1);
  dim3 gridC(NCHUNK, 16);
  gemm2_partial<<<gridC, 256, (32 * SH + 128 * SW2) * sizeof(float), stream>>>(h1, W2, partials);
  dim3 gridR1(G * DMID / 256, 8);
  gemm2_reduce1<<<gridR1, 256, 0, stream>>>(partials, partials2);
  gemm2_reduce2<<<G * DMID / 256, 256, 0, stream>>>(partials2, b2, h2);
  head_kernel<<<G / 2, 256, 0, stream>>>(h2, W3, b3, ts, pair_sq);
  loss_kernel<<<1, 256, 0, stream>>>(pair_sq, (float*)d_out);
}

// Round 4
// 327.733 us; speedup vs baseline: 1.0481x; 1.0481x over previous
//
#include <hip/hip_runtime.h>
#include <math.h>

#define G 512
#define N 400
#define D 128
#define K 200
#define DOUT 512
#define DMID 32
#define GK (G*K)      // 102400
#define KD (K*D)      // 25600
#define NCHUNK 200    // GEMM2 k-chunks of 128

#define SH  129       // sHt stride (GEMM2)
#define SW2 36        // padded stride for W2T tile (GEMM2)

#define NT 13         // m-tiles of 32 rows in gemm1_pool (416 slots, 400 valid)
#define TPB 512       // threads per block of gemm1_pool (8 waves)

// dynamic LDS layout for gemm1_pool (bytes):
//   float  s_acc[200][128]   102400
//   int    s_ids[400]          1600
//   int    s_cnt[200]           800
#define G1_LDS (102400 + 1600 + 800)  // 104800

__device__ __forceinline__ float relu(float v) { return fmaxf(v, 0.0f); }

typedef __attribute__((ext_vector_type(8))) short short8b;   // 8 bf16 = 4 VGPR
typedef __attribute__((ext_vector_type(16))) float floatx16; // mfma 32x32 acc

__device__ __forceinline__ ushort f2bf(float f) {  // fp32 -> bf16 (RNE)
  unsigned u = __float_as_uint(f);
  unsigned r = (u + 0x7FFFu + ((u >> 16) & 1u)) >> 16;
  return (ushort)r;
}
__device__ __forceinline__ float bf2f(ushort h) {
  return __uint_as_float(((unsigned)h) << 16);
}

// Native non-returning LDS float add (single DS op, no CAS retry loop).
__device__ __forceinline__ void lds_fadd(float* p, float v) {
  asm volatile("ds_add_f32 %0, %1"
               :
               : "v"((unsigned)(unsigned long long)p), "v"(v)
               : "memory");
}

// ---------------- K1b: W1 -> fragment-major hi/lo bf16 (B-operand prep) ----------------
// layout: wh[nt][ks][l][i] holds W1[k*D + n], k = ks*16 + (l>>5)*8 + i, n = nt*32 + (l&31)
__global__ __launch_bounds__(256) void w1prep(
    const float* __restrict__ W1, ushort* __restrict__ wh, ushort* __restrict__ wl) {
  const int idx = blockIdx.x * 256 + threadIdx.x;  // < 16384
  const int i = idx & 7, l = (idx >> 3) & 63, ks = (idx >> 9) & 7, nt = idx >> 12;
  const int k = ks * 16 + (l >> 5) * 8 + i;
  const int n = nt * 32 + (l & 31);
  const float v = W1[k * D + n];
  const ushort h = f2bf(v);
  wh[idx] = h;
  wl[idx] = f2bf(v - bf2f(h));
}

// ---------------- K1: dense GEMM (x @ W1) then segment-mean pooling ----------------
// One block per g, 8 waves, BARRIER-FREE main loop. The MFMA A-fragment for
// lane l is 8 CONSECUTIVE k-values of one x-row, so A-frags are built directly
// in registers from two float4 global loads — no LDS staging, no cross-wave
// dependency, no per-tile __syncthreads (whose compiler-emitted vmcnt(0) drain
// at 1 block/CU serialized the whole CU = the 310 us pathology). The ds_add_f32
// scatter into s_acc[cluster][n] is commutative: ordering only matters at the
// single final barrier. Wave w: nt = w&3, ksbase = (w>>2)*4 (K split, partial
// sums combine in the scatter). Epilogue: 1/cnt, +b1, relu, float4 store.
__global__ __launch_bounds__(TPB, 1) void gemm1_pool(
    const float* __restrict__ x, const int* __restrict__ cluster,
    const ushort* __restrict__ wh, const ushort* __restrict__ wl,
    const float* __restrict__ b1, float* __restrict__ h1) {
  extern __shared__ char smem[];
  float* s_acc = (float*)smem;              // [200][128]
  int*   s_ids = (int*)(smem + 102400);     // [400]
  int*   s_cnt = s_ids + 400;               // [200]

  const int g = blockIdx.x;
  const int tid = threadIdx.x;
  const int lane = tid & 63;
  const int w = tid >> 6;
  const int nt = w & 3, ksbase = (w >> 2) * 4;

  const float* xg = x + (size_t)g * N * D;

  // per-lane A-frag geometry: row m = lane&31, k-base = ksbase*16 + (lane>>5)*8
  const int rowin = lane & 31;
  const int kbase = ksbase * 16 + ((lane >> 5) << 3);

  // LOADT: tile MT's A-data for this wave's 4 ks-slots -> 8 float4 regs
#define LOADT(MT, B0, B1)                                                   \
  {                                                                         \
    int rr = (MT) * 32 + rowin; rr = rr < N ? rr : N - 1;                   \
    const float* p = xg + (size_t)rr * D + kbase;                           \
    _Pragma("unroll")                                                       \
    for (int kk = 0; kk < 4; ++kk) {                                        \
      B0[kk] = *(const float4*)(p + kk * 16);                               \
      B1[kk] = *(const float4*)(p + kk * 16 + 4);                           \
    }                                                                       \
  }

  // TILE_MFMA: convert 8 floats/ks to hi/lo bf16 frags in regs, 3 MFMAs per ks
#define TILE_MFMA(B0, B1)                                                   \
  _Pragma("unroll")                                                         \
  for (int kk = 0; kk < 4; ++kk) {                                          \
    float vv[8] = {B0[kk].x, B0[kk].y, B0[kk].z, B0[kk].w,                  \
                   B1[kk].x, B1[kk].y, B1[kk].z, B1[kk].w};                 \
    short8b ah, al;                                                         \
    _Pragma("unroll")                                                       \
    for (int e = 0; e < 8; ++e) {                                           \
      const ushort hh = f2bf(vv[e]);                                        \
      ah[e] = (short)hh;                                                    \
      al[e] = (short)f2bf(vv[e] - bf2f(hh));                                \
    }                                                                       \
    acc = __builtin_amdgcn_mfma_f32_32x32x16_bf16(ah, Bh[kk], acc, 0, 0, 0);\
    acc = __builtin_amdgcn_mfma_f32_32x32x16_bf16(ah, Bl[kk], acc, 0, 0, 0);\
    acc = __builtin_amdgcn_mfma_f32_32x32x16_bf16(al, Bh[kk], acc, 0, 0, 0);\
  }

  float4 LA0[4], LA1[4], LB0[4], LB1[4];
  LOADT(0, LA0, LA1);  // issue tile-0 loads ASAP

  // zero accumulator + counts
  for (int i = tid; i < K * D / 4; i += TPB)
    ((float4*)s_acc)[i] = make_float4(0.f, 0.f, 0.f, 0.f);
  if (tid < K) s_cnt[tid] = 0;
  __syncthreads();  // B1: zeroing visible

  if (tid < N) {
    const int id = cluster[g * N + tid];
    s_ids[tid] = id;
    atomicAdd(&s_cnt[id], 1);
  }

  // hoist W1 B-frags for this wave (nt, 4 ks) into registers
  short8b Bh[4], Bl[4];
#pragma unroll
  for (int kk = 0; kk < 4; ++kk) {
    const int ks = ksbase + kk;
    Bh[kk] = *(const short8b*)&wh[((nt * 8 + ks) * 64 + lane) * 8];
    Bl[kk] = *(const short8b*)&wl[((nt * 8 + ks) * 64 + lane) * 8];
  }
  __syncthreads();  // B2: ids + counts ready; last block-wide sync before epilogue

  const int col = lane & 31;
  const int rbase4 = 4 * (lane >> 5);

  // ---- main loop: ZERO barriers; each wave runs free, loads 1 tile ahead ----
  for (int mt = 0; mt < NT; ++mt) {
    if (mt + 1 < NT) {  // issue next tile into the other buffer
      if (mt & 1) { LOADT(mt + 1, LA0, LA1); }
      else        { LOADT(mt + 1, LB0, LB1); }
    }

    // gather this tile's 16 cluster ids (broadcast LDS reads, batched)
    const int rowbase = mt * 32 + rbase4;
    int ids[16];
#pragma unroll
    for (int q = 0; q < 4; ++q) {
      const int4 t = *(const int4*)&s_ids[rowbase + 8 * q];  // rows +0..3 of group q
      ids[q * 4 + 0] = t.x; ids[q * 4 + 1] = t.y;
      ids[q * 4 + 2] = t.z; ids[q * 4 + 3] = t.w;
    }

    floatx16 acc;
#pragma unroll
    for (int e = 0; e < 16; ++e) acc[e] = 0.0f;

    if (mt & 1) { TILE_MFMA(LB0, LB1) }
    else        { TILE_MFMA(LA0, LA1) }

    // scatter y-fragments into per-cluster accumulator (bank = col: conflict-free)
#pragma unroll
    for (int e = 0; e < 16; ++e) {
      const int r = rowbase + (e & 3) + 8 * (e >> 2);
      if (r < N) lds_fadd(&s_acc[ids[e] * D + nt * 32 + col], acc[e]);
    }
  }
#undef LOADT
#undef TILE_MFMA

  // drain this wave's untracked ds_adds, then sync all waves once
  asm volatile("s_waitcnt lgkmcnt(0)" ::: "memory");
  __syncthreads();

  // ---- epilogue: mean + bias + relu, coalesced float4 stores ----
  float* og = h1 + (size_t)g * KD;
  for (int i = tid; i < K * D / 4; i += TPB) {
    const int row = i >> 5;
    const int c = s_cnt[row];
    const float iv = 1.0f / (float)(c > 0 ? c : 1);
    const float4 a = ((const float4*)s_acc)[i];
    const float4 bb = *(const float4*)&b1[(i & 31) * 4];
    float4 o;
    o.x = relu(fmaf(a.x, iv, bb.x));
    o.y = relu(fmaf(a.y, iv, bb.y));
    o.z = relu(fmaf(a.z, iv, bb.z));
    o.w = relu(fmaf(a.w, iv, bb.w));
    ((float4*)og)[i] = o;
  }
}

// ---------------- K3: GEMM2 partials (32-row g-blocks) ----------------
__global__ __launch_bounds__(256) void gemm2_partial(
    const float* __restrict__ h1, const float* __restrict__ W2,
    float* __restrict__ partials) {
  extern __shared__ float smemf[];
  float* sHt = smemf;            // [32][SH]
  float* sWT = smemf + 32 * SH;  // [128][SW2]
  const int kc = blockIdx.x;     // 0..199
  const int gb = blockIdx.y;     // 0..15
  const int k0 = kc * 128, g0 = gb * 32;
  const int tid = threadIdx.x;

  for (int i = tid; i < 32 * 128; i += 256) {
    const int r = i >> 7, k = i & 127;
    sHt[r * SH + k] = h1[(size_t)(g0 + r) * KD + k0 + k];
  }
  for (int i = tid; i < 32 * 128; i += 256) {
    const int j = i >> 7, k = i & 127;
    sWT[k * SW2 + j] = W2[(size_t)j * KD + k0 + k];
  }
  __syncthreads();

  const int jt = tid & 7;   // j block of 4
  const int gt = tid >> 3;  // one g row each (32)
  float acc[4];
#pragma unroll
  for (int j = 0; j < 4; j++) acc[j] = 0.0f;

  for (int k = 0; k < 128; ++k) {
    const float h = sHt[gt * SH + k];
    const float4 w0 = *(const float4*)&sWT[k * SW2 + jt * 4];
    acc[0] = fmaf(h, w0.x, acc[0]); acc[1] = fmaf(h, w0.y, acc[1]);
    acc[2] = fmaf(h, w0.z, acc[2]); acc[3] = fmaf(h, w0.w, acc[3]);
  }

  float* pp = partials + ((size_t)kc * G + g0 + gt) * DMID + jt * 4;
  *(float4*)&pp[0] = make_float4(acc[0], acc[1], acc[2], acc[3]);
}

// ---------------- K4a: reduce stage 1 (200 -> 8), grid (64, 8) ----------------
__global__ __launch_bounds__(256) void gemm2_reduce1(
    const float* __restrict__ partials, float* __restrict__ partials2) {
  const int idx = blockIdx.x * 256 + threadIdx.x;  // < G*DMID
  const int cg = blockIdx.y;                        // 0..7
  float s = 0.0f;
  for (int c = cg * 25; c < cg * 25 + 25; ++c)
    s += partials[(size_t)c * G * DMID + idx];
  partials2[(size_t)cg * G * DMID + idx] = s;
}

// ---------------- K4b: reduce stage 2 (8 -> h2) ----------------
__global__ __launch_bounds__(256) void gemm2_reduce2(
    const float* __restrict__ partials2, const float* __restrict__ b2,
    float* __restrict__ h2) {
  const int idx = blockIdx.x * 256 + threadIdx.x;  // < G*DMID
  const int j = idx & 31;
  float s = 0.0f;
#pragma unroll
  for (int c = 0; c < 8; ++c) s += partials2[(size_t)c * G * DMID + idx];
  h2[idx] = relu(s + b2[j]);
}

// ---------------- K5: GEMM3 + cosine + per-pair squared error ----------------
__global__ __launch_bounds__(256) void head_kernel(
    const float* __restrict__ h2, const float* __restrict__ W3,
    const float* __restrict__ b3, const float* __restrict__ ts,
    float* __restrict__ pair_sq) {
  __shared__ float sA[DMID], sB[DMID];
  __shared__ float rdot[4], rna[4], rnb[4];
  const int p = blockIdx.x;
  const int tid = threadIdx.x;
  if (tid < DMID) sA[tid] = h2[(size_t)(2 * p) * DMID + tid];
  else if (tid < 2 * DMID) sB[tid - DMID] = h2[(size_t)(2 * p + 1) * DMID + (tid - DMID)];
  __syncthreads();

  float dot = 0.0f, na = 0.0f, nb = 0.0f;
#pragma unroll
  for (int rep = 0; rep < 2; ++rep) {
    const int o = rep * 256 + tid;
    const float* w = W3 + (size_t)o * DMID;
    float accA = b3[o], accB = accA;
#pragma unroll
    for (int m = 0; m < DMID; m += 4) {
      const float4 wv = *(const float4*)&w[m];
      accA = fmaf(sA[m], wv.x, accA); accB = fmaf(sB[m], wv.x, accB);
      accA = fmaf(sA[m + 1], wv.y, accA); accB = fmaf(sB[m + 1], wv.y, accB);
      accA = fmaf(sA[m + 2], wv.z, accA); accB = fmaf(sB[m + 2], wv.z, accB);
      accA = fmaf(sA[m + 3], wv.w, accA); accB = fmaf(sB[m + 3], wv.w, accB);
    }
    const float a = relu(accA), b = relu(accB);
    dot = fmaf(a, b, dot); na = fmaf(a, a, na); nb = fmaf(b, b, nb);
  }
#pragma unroll
  for (int off = 32; off >= 1; off >>= 1) {
    dot += __shfl_down(dot, off);
    na  += __shfl_down(na, off);
    nb  += __shfl_down(nb, off);
  }
  const int wave = tid >> 6, lane = tid & 63;
  if (lane == 0) { rdot[wave] = dot; rna[wave] = na; rnb[wave] = nb; }
  __syncthreads();
  if (tid == 0) {
    const float dt = rdot[0] + rdot[1] + rdot[2] + rdot[3];
    const float nA = rna[0] + rna[1] + rna[2] + rna[3];
    const float nB = rnb[0] + rnb[1] + rnb[2] + rnb[3];
    const float n1 = fmaxf(sqrtf(nA), 1e-6f);
    const float n2 = fmaxf(sqrtf(nB), 1e-6f);
    const float sc = dt / (n1 * n2);
    const float e = sc - ts[p];
    pair_sq[p] = e * e;
  }
}

// ---------------- K6: final mean ----------------
__global__ __launch_bounds__(256) void loss_kernel(
    const float* __restrict__ pair_sq, float* __restrict__ out) {
  __shared__ float red[4];
  const int tid = threadIdx.x;
  float v = pair_sq[tid];
#pragma unroll
  for (int off = 32; off >= 1; off >>= 1) v += __shfl_down(v, off);
  const int wave = tid >> 6, lane = tid & 63;
  if (lane == 0) red[wave] = v;
  __syncthreads();
  if (tid == 0) out[0] = (red[0] + red[1] + red[2] + red[3]) * (1.0f / 256.0f);
}

extern "C" void kernel_launch(void* const* d_in, const int* in_sizes, int n_in,
                              void* d_out, int out_size, void* d_ws, size_t ws_size,
                              hipStream_t stream) {
  const float* x       = (const float*)d_in[0];
  const int*   cluster = (const int*)d_in[1];
  const float* ts      = (const float*)d_in[2];
  const float* W1      = (const float*)d_in[3];
  const float* b1      = (const float*)d_in[4];
  const float* W2      = (const float*)d_in[5];
  const float* b2      = (const float*)d_in[6];
  const float* W3      = (const float*)d_in[7];
  const float* b3      = (const float*)d_in[8];

  float* ws = (float*)d_ws;
  float* h1        = ws;                                   // GK*D
  float* partials  = h1 + (size_t)GK * D;                  // NCHUNK*G*DMID
  float* h2        = partials + (size_t)NCHUNK * G * DMID; // G*DMID
  float* pair_sq   = h2 + (size_t)G * DMID;                // 256
  float* partials2 = pair_sq + 256;                        // 8*G*DMID
  ushort* wfrag_hi = (ushort*)(partials2 + 8 * G * DMID);  // 16384 bf16
  ushort* wfrag_lo = wfrag_hi + 16384;                     // 16384 bf16

  // allow >64 KB dynamic LDS for gemm1_pool (host-side attr, graph-capture safe)
  static bool attr_set = false;
  if (!attr_set) {
    (void)hipFuncSetAttribute((const void*)gemm1_pool,
                              hipFuncAttributeMaxDynamicSharedMemorySize,
                              160 * 1024);
    attr_set = true;
  }

  w1prep<<<16384 / 256, 256, 0, stream>>>(W1, wfrag_hi, wfrag_lo);
  gemm1_pool<<<G, TPB, G1_LDS, stream>>>(x, cluster, wfrag_hi, wfrag_lo, b1, h1);
  dim3 gridC(NCHUNK, 16);
  gemm2_partial<<<gridC, 256, (32 * SH + 128 * SW2) * sizeof(float), stream>>>(h1, W2, partials);
  dim3 gridR1(G * DMID / 256, 8);
  gemm2_reduce1<<<gridR1, 256, 0, stream>>>(partials, partials2);
  gemm2_reduce2<<<G * DMID / 256, 256, 0, stream>>>(partials2, b2, h2);
  head_kernel<<<G / 2, 256, 0, stream>>>(h2, W3, b3, ts, pair_sq);
  loss_kernel<<<1, 256, 0, stream>>>(pair_sq, (float*)d_out);
}